// Round 9
// baseline (224.662 us; speedup 1.0000x reference)
//
#include <hip/hip_runtime.h>

// ---------------------------------------------------------------------------
// CausalSelfAttention (B=1, T=2048, DIM=1024, H=8, hd=128, scale=0.12)
// R9 = R8 with the workspace-aliasing bug fixed: rope tables moved to the
//     ybf region (dead until attn_combine). R8 had put them inside wqkv,
//     corrupting V weights with float bit patterns (~1/256 decode as bf16
//     NaN) -> NaN output.
// Structure: cast -> gemm1_fused (qkv GEMM + rmsnorm/rope/v-combine epilogue)
//            -> attn_part (dbuf K+V, S^T trick, x16 PV) -> combine -> gemm2.
// MFMA layouts (m89/m91): x32: A[m=ln][k=quad*8+j]; x16: A[m=ln][k=quad*4+j];
//   B mirrors with n=ln; C/D: row=quad*4+reg, col=ln (quad=lane>>4)
// ---------------------------------------------------------------------------

typedef __attribute__((ext_vector_type(8))) short short8;      // 8 bf16
typedef __attribute__((ext_vector_type(4))) short short4b;     // 4 bf16
typedef __attribute__((ext_vector_type(4))) float fx4;         // MFMA acc
typedef __attribute__((ext_vector_type(8))) unsigned short ushort8;
typedef __attribute__((ext_vector_type(4))) unsigned short ushort4v;
typedef __attribute__((ext_vector_type(2))) unsigned short ushort2v;
typedef __attribute__((ext_vector_type(4))) float float4v;

#define T_SEQ 2048
#define NH 8
#define HD 128

__device__ __forceinline__ unsigned short f2bf(float f) {
  union { float f; unsigned u; } v; v.f = f;
  unsigned u = v.u;
  u += 0x7fffu + ((u >> 16) & 1u);        // RNE, finite inputs only
  return (unsigned short)(u >> 16);
}
__device__ __forceinline__ short bf_t(float f) {  // truncate (fast)
  union { float f; unsigned u; } v; v.f = f;
  return (short)(v.u >> 16);
}
__device__ __forceinline__ float bf2f(unsigned short h) {
  union { unsigned u; float f; } v; v.u = ((unsigned)h) << 16;
  return v.f;
}

// async global->LDS, 16B/lane; LDS dest = wave-uniform base + lane*16
typedef __attribute__((address_space(1))) unsigned int glb_u32;
typedef __attribute__((address_space(3))) unsigned int lds_u32;
__device__ __forceinline__ void gl_lds16(const unsigned short* g, unsigned short* l) {
  __builtin_amdgcn_global_load_lds((const glb_u32*)g, (lds_u32*)l, 16, 0, 0);
}

// ---------------------------------------------------------------------------
// Kernel 0: cast x (2M), qkv_w (3M), c_proj_w (1M) fp32 -> bf16 contiguous.
// ---------------------------------------------------------------------------
__global__ __launch_bounds__(256) void cast3_kernel(
    const float* __restrict__ x, const float* __restrict__ w1,
    const float* __restrict__ w2, unsigned short* __restrict__ o) {
  long q = (long)blockIdx.x * 256 + threadIdx.x;   // quad index
  const float* src;
  if (q < 524288)        src = x  + 4 * q;
  else if (q < 1310720)  src = w1 + 4 * (q - 524288);
  else                   src = w2 + 4 * (q - 1310720);
  float4v v = *(const float4v*)src;
  ushort4v r;
  r[0] = f2bf(v[0]); r[1] = f2bf(v[1]); r[2] = f2bf(v[2]); r[3] = f2bf(v[3]);
  *(ushort4v*)(o + 4 * q) = r;
}

// ---------------------------------------------------------------------------
// Kernel 0b: rotary tables cos/sin[t][d], d<32. 65536 entries each.
// ---------------------------------------------------------------------------
__global__ __launch_bounds__(256) void rope_tab(
    float* __restrict__ rc, float* __restrict__ rs) {
  int idx = blockIdx.x * 256 + threadIdx.x;        // 0..65535
  int t = idx >> 5, d = idx & 31;
  float ang = exp2f(-10.0f * (float)d / 31.0f);    // (1/1024)^(d/31)
  float th = (float)t * ang;
  rc[idx] = __cosf(th);
  rs[idx] = __sinf(th);
}

// ---------------------------------------------------------------------------
// Kernel 1: fused qkv GEMM + prep. C[2048,3072] = x_bf * wqkv^T in tiles of
// BM=64 x BN=128 (grid 24x32; col tile == one (which,head)); BK=64 dbuf,
// one barrier/iter, async staging, (row>>1) XOR swizzle.
// Epilogue: accs -> LDS fp32 [64][132];
//   which<2 : per-row rmsnorm (4 thr/row, 2 shfl) + rotary (table) -> qh/kh
//   which==2: l0*acc + l1*ve -> interleaved transpose -> vt[h][d][t']
//             (p = kt1*32 + q4*8 + kt0*4 + j for direct x16 PV A-frag reads)
// ---------------------------------------------------------------------------
__global__ __launch_bounds__(256) void gemm1_fused(
    const unsigned short* __restrict__ A, const unsigned short* __restrict__ B,
    const float* __restrict__ ve, const float* __restrict__ lambdas,
    const float* __restrict__ rc, const float* __restrict__ rs,
    unsigned short* __restrict__ qh, unsigned short* __restrict__ kh,
    unsigned short* __restrict__ vt) {
  constexpr int K = 1024;
  __shared__ unsigned short smem[2][12288];   // [buf][A:0..4096 | B:4096..12288]
  const int tid = threadIdx.x;
  const int wave = tid >> 6, lane = tid & 63;
  const int ln = lane & 15, quad = lane >> 4;
  const int wm = wave & 1, wn = wave >> 1;
  const long arow0 = (long)blockIdx.y * 64;
  const long brow0 = (long)blockIdx.x * 128;
  const int which = blockIdx.x >> 3, h = blockIdx.x & 7;

  const unsigned short* gsrc[6];
  unsigned short* ldst[6];
  for (int i = 0; i < 6; ++i) {
    int s = wave * 6 + i;
    int isB = s >= 8;
    int srel = isB ? s - 8 : s;
    int li = srel * 64 + lane;                // 16B chunk index in region
    int row = li >> 3, posc = li & 7;
    int c = posc ^ ((row >> 1) & 7);
    gsrc[i] = (isB ? B + brow0 * (long)K : A + arow0 * (long)K)
              + (long)row * K + c * 8;
    ldst[i] = &smem[0][(isB ? 4096 : 0) + srel * 512];
  }
  for (int i = 0; i < 6; ++i) gl_lds16(gsrc[i], ldst[i]);   // prologue

  fx4 acc[2][4] = {};
  int cur = 0;
  for (int k0 = 0; k0 < K; k0 += 64, cur ^= 1) {
    __syncthreads();
    if (k0 + 64 < K)
      for (int i = 0; i < 6; ++i)
        gl_lds16(gsrc[i] + k0 + 64, ldst[i] + (cur ^ 1) * 12288);
    const unsigned short* ash = &smem[cur][0];
    const unsigned short* bsh = &smem[cur][4096];
    short8 af[2][2], bfr[2][4];
    for (int kq = 0; kq < 2; ++kq) {
      for (int mt = 0; mt < 2; ++mt) {
        int m = wm * 32 + mt * 16 + ln;
        int pos = (kq * 4 + quad) ^ ((m >> 1) & 7);
        af[kq][mt] = *(const short8*)&ash[m * 64 + pos * 8];
      }
      for (int nt = 0; nt < 4; ++nt) {
        int n = wn * 64 + nt * 16 + ln;
        int pos = (kq * 4 + quad) ^ ((n >> 1) & 7);
        bfr[kq][nt] = *(const short8*)&bsh[n * 64 + pos * 8];
      }
    }
    for (int kq = 0; kq < 2; ++kq)
      for (int mt = 0; mt < 2; ++mt)
        for (int nt = 0; nt < 4; ++nt)
          acc[mt][nt] = __builtin_amdgcn_mfma_f32_16x16x32_bf16(
              af[kq][mt], bfr[kq][nt], acc[mt][nt], 0, 0, 0);
  }

  // ---- epilogue: accs -> LDS fp32 [64][132] ----
  __syncthreads();
  float* esh = (float*)&smem[0][0];           // 64*132*4 = 33.8KB < 48KB
  if (which == 2) {
    const float l0 = lambdas[0], l1 = lambdas[1];
    for (int mt = 0; mt < 2; ++mt)
      for (int nt = 0; nt < 4; ++nt)
        for (int r = 0; r < 4; ++r) {
          int row = wm * 32 + mt * 16 + quad * 4 + r;
          int col = wn * 64 + nt * 16 + ln;
          float vev = ve[(arow0 + row) * 1024 + h * 128 + col];
          esh[row * 132 + col] = l0 * acc[mt][nt][r] + l1 * vev;
        }
  } else {
    for (int mt = 0; mt < 2; ++mt)
      for (int nt = 0; nt < 4; ++nt)
        for (int r = 0; r < 4; ++r) {
          int row = wm * 32 + mt * 16 + quad * 4 + r;
          int col = wn * 64 + nt * 16 + ln;
          esh[row * 132 + col] = acc[mt][nt][r];
        }
  }
  __syncthreads();

  if (which < 2) {
    // 4 threads per row; thread handles 16 rotary pairs (d, d+64), d=qq*16+j
    const int lrow = tid >> 2, qq = tid & 3;
    const long t = arow0 + lrow;
    float4v x1[4], x2[4];
    float ss = 0.f;
    for (int i = 0; i < 4; ++i) {
      x1[i] = *(const float4v*)&esh[lrow * 132 + qq * 16 + 4 * i];
      x2[i] = *(const float4v*)&esh[lrow * 132 + 64 + qq * 16 + 4 * i];
      ss += x1[i][0]*x1[i][0] + x1[i][1]*x1[i][1] + x1[i][2]*x1[i][2] + x1[i][3]*x1[i][3];
      ss += x2[i][0]*x2[i][0] + x2[i][1]*x2[i][1] + x2[i][2]*x2[i][2] + x2[i][3]*x2[i][3];
    }
    ss += __shfl_xor(ss, 1);
    ss += __shfl_xor(ss, 2);
    float rn = rsqrtf(ss * (1.0f / 128.0f) + 1.1920929e-7f);
    float4v cv[4], sv[4];
    if (qq < 2) {
      for (int i = 0; i < 4; ++i) {
        cv[i] = *(const float4v*)&rc[t * 32 + qq * 16 + 4 * i];
        sv[i] = *(const float4v*)&rs[t * 32 + qq * 16 + 4 * i];
      }
    } else {
      for (int i = 0; i < 4; ++i) { cv[i] = float4v{1,1,1,1}; sv[i] = float4v{0,0,0,0}; }
    }
    ushort8 o1[2], o2[2];
    for (int j = 0; j < 16; ++j) {
      float a = x1[j >> 2][j & 3], b = x2[j >> 2][j & 3];
      float c = cv[j >> 2][j & 3], s = sv[j >> 2][j & 3];
      o1[j >> 3][j & 7] = f2bf(( a * c + b * s) * rn);
      o2[j >> 3][j & 7] = f2bf((-a * s + b * c) * rn);
    }
    unsigned short* dst = (which ? kh : qh) + ((long)h * T_SEQ + t) * 128 + qq * 16;
    *(ushort8*)(dst)      = o1[0];
    *(ushort8*)(dst + 8)  = o1[1];
    *(ushort8*)(dst + 64)     = o2[0];
    *(ushort8*)(dst + 64 + 8) = o2[1];
  } else {
    // transpose out: thread (d, half), interleaved kv mapping
    const int d = tid >> 1, half = tid & 1;
    unsigned short* dst = vt + ((long)h * HD + d) * T_SEQ + arow0 + half * 32;
    for (int g = 0; g < 8; ++g) {
      int p0 = half * 32 + g * 4;
      int kv0 = ((p0 >> 5) & 1) * 32 + ((p0 >> 2) & 1) * 16 + ((p0 >> 3) & 3) * 4;
      ushort4v o;
      for (int j = 0; j < 4; ++j) o[j] = f2bf(esh[(kv0 + j) * 132 + d]);
      *(ushort4v*)(dst + g * 4) = o;
    }
  }
}

// ---------------------------------------------------------------------------
// GEMM (BT): C[M,N] = A[M,K]*B[N,K]^T, bf16 in / fp32 acc. Tile BM x BN x BK,
// 4 waves (2x2). Double-buffered LDS, ONE barrier per K-iter.
// ---------------------------------------------------------------------------
template <bool OUT_BF16, int BM, int BN, int BK>
__global__ __launch_bounds__(256) void gemm_bt5(
    const unsigned short* __restrict__ A, const unsigned short* __restrict__ B,
    void* __restrict__ Cp, int M, int N, int K) {
  constexpr int MT = BM / 32;
  constexpr int NT = BN / 32;
  constexpr int KQ = BK / 32;
  constexpr int CPR = BK / 8;
  constexpr int ASEG = BM * BK / 512;
  constexpr int NLOAD = (BM + BN) * BK / 512 / 4;
  __shared__ unsigned short a_sh[2][BM * BK];
  __shared__ unsigned short b_sh[2][BN * BK];
  const int tid = threadIdx.x;
  const int wave = tid >> 6, lane = tid & 63;
  const int ln = lane & 15, quad = lane >> 4;
  const int wm = wave & 1, wn = wave >> 1;
  const long arow0 = (long)blockIdx.y * BM;
  const long brow0 = (long)blockIdx.x * BN;

  const unsigned short* gsrc[NLOAD];
  unsigned short* ldst[NLOAD];
  int bstr[NLOAD];
  for (int i = 0; i < NLOAD; ++i) {
    int s = wave * NLOAD + i;
    int isB = s >= ASEG;
    int srel = isB ? s - ASEG : s;
    int li = srel * 64 + lane;
    int row = li / CPR, posc = li % CPR;
    int c = posc ^ ((row >> 1) & (CPR - 1));
    gsrc[i] = (isB ? B + brow0 * (long)K : A + arow0 * (long)K)
              + (long)row * K + c * 8;
    ldst[i] = (isB ? &b_sh[0][0] : &a_sh[0][0]) + srel * 512;
    bstr[i] = (isB ? BN : BM) * BK;
  }
  for (int i = 0; i < NLOAD; ++i) gl_lds16(gsrc[i], ldst[i]);

  fx4 acc[MT][NT] = {};
  int cur = 0;
  for (int k0 = 0; k0 < K; k0 += BK, cur ^= 1) {
    __syncthreads();
    if (k0 + BK < K)
      for (int i = 0; i < NLOAD; ++i)
        gl_lds16(gsrc[i] + k0 + BK, ldst[i] + (cur ^ 1) * bstr[i]);
    const unsigned short* ash = &a_sh[cur][0];
    const unsigned short* bsh = &b_sh[cur][0];
    short8 af[KQ][MT], bfr[KQ][NT];
    for (int kq = 0; kq < KQ; ++kq) {
      for (int mt = 0; mt < MT; ++mt) {
        int m = wm * (BM / 2) + mt * 16 + ln;
        int pos = (kq * 4 + quad) ^ ((m >> 1) & (CPR - 1));
        af[kq][mt] = *(const short8*)&ash[m * BK + pos * 8];
      }
      for (int nt = 0; nt < NT; ++nt) {
        int n = wn * (BN / 2) + nt * 16 + ln;
        int pos = (kq * 4 + quad) ^ ((n >> 1) & (CPR - 1));
        bfr[kq][nt] = *(const short8*)&bsh[n * BK + pos * 8];
      }
    }
    for (int kq = 0; kq < KQ; ++kq)
      for (int mt = 0; mt < MT; ++mt)
        for (int nt = 0; nt < NT; ++nt)
          acc[mt][nt] = __builtin_amdgcn_mfma_f32_16x16x32_bf16(
              af[kq][mt], bfr[kq][nt], acc[mt][nt], 0, 0, 0);
  }
  for (int mt = 0; mt < MT; ++mt)
    for (int nt = 0; nt < NT; ++nt)
      for (int r = 0; r < 4; ++r) {
        long row = arow0 + wm * (BM / 2) + mt * 16 + quad * 4 + r;
        long col = brow0 + wn * (BN / 2) + nt * 16 + ln;
        float v = acc[mt][nt][r];
        if constexpr (OUT_BF16)
          ((unsigned short*)Cp)[row * N + col] = f2bf(v);
        else
          ((float*)Cp)[row * N + col] = v;
      }
}

// ---------------------------------------------------------------------------
// Kernel 3a: chunked flash attention partials (q-tile 128, 2 q-sets/wave).
// Grid (qt=16, h=8, ch=8); chunk covers 64-kv tiles [4ch, min(4ch+3, 2qt+1)].
// K,V double-buffered; ONE barrier per jt; full-iteration async prefetch.
// S^T = K*Q^T; fixed-max softmax; PV via mfma_16x16x16 (P already B-layout).
// Partials: pp=h*72+cbase(qt)+ch; Yp bf16 [pp][128][128], lp fp32 [pp][128].
// ---------------------------------------------------------------------------
#define ATT_C1 0.17312340490667562f   // 0.12 * log2(e)
#define ATT_C2 23.083120654223415f    // 16   * log2(e)

__global__ __launch_bounds__(256, 2) void attn_part(
    const unsigned short* __restrict__ qh, const unsigned short* __restrict__ kh,
    const unsigned short* __restrict__ vt, unsigned short* __restrict__ Yp,
    float* __restrict__ lp) {
  __shared__ unsigned short kbuf[2][8192];    // 2 x 16KB: K tile [64][128]
  __shared__ unsigned short vbuf[2][8192];    // 2 x 16KB: V^T tile [128][64]
  const int tid = threadIdx.x;
  const int wave = tid >> 6, lane = tid & 63;
  const int ln = lane & 15, quad = lane >> 4;
  const int qt = blockIdx.x, h = blockIdx.y, ch = blockIdx.z;
  const int jmax = 2 * qt + 1;
  const int j0 = ch * 4;
  if (j0 > jmax) return;                      // uniform per block
  const int j1 = min(j0 + 3, jmax);

  int qg[2];
  short8 qf[2][4];
  for (int s = 0; s < 2; ++s) {
    qg[s] = qt * 128 + wave * 32 + s * 16 + ln;
    const unsigned short* qbase = qh + ((long)h * T_SEQ + qg[s]) * 128;
    for (int kc = 0; kc < 4; ++kc)
      qf[s][kc] = *(const short8*)(qbase + kc * 32 + quad * 8);
  }
  fx4 accy[2][8] = {};
  float l_loc[2] = {0.f, 0.f};

  const unsigned short* kg[4]; unsigned short* kl[4];
  const unsigned short* vg[4]; unsigned short* vl[4];
  for (int i = 0; i < 4; ++i) {
    int s = wave * 4 + i;
    { int li = s * 64 + lane; int row = li >> 4, posc = li & 15;
      int c = posc ^ (row & 15);
      kg[i] = kh + ((long)h * T_SEQ + row) * 128 + c * 8;
      kl[i] = &kbuf[0][s * 512]; }
    { int li = s * 64 + lane; int row = li >> 3, posc = li & 7;
      int c = posc ^ (row & 7);
      vg[i] = vt + ((long)h * HD + row) * T_SEQ + c * 8;
      vl[i] = &vbuf[0][s * 512]; }
  }
  for (int i = 0; i < 4; ++i) gl_lds16(kg[i] + (long)j0 * 8192, kl[i]);
  for (int i = 0; i < 4; ++i) gl_lds16(vg[i] + (long)j0 * 64, vl[i]);

  int cur = 0;
  for (int jt = j0; jt <= j1; ++jt, cur ^= 1) {
    __syncthreads();                // drains async loads; publishes buf[cur]
    if (jt < j1) {                  // full-iteration prefetch into cur^1
      int nb = (cur ^ 1) * 8192;
      for (int i = 0; i < 4; ++i) gl_lds16(kg[i] + (long)(jt + 1) * 8192, kl[i] + nb);
      for (int i = 0; i < 4; ++i) gl_lds16(vg[i] + (long)(jt + 1) * 64, vl[i] + nb);
    }
    const unsigned short* kb_ = &kbuf[cur][0];
    fx4 s4[2][4];
    for (int kt = 0; kt < 4; ++kt) {
      s4[0][kt] = fx4{0.f, 0.f, 0.f, 0.f};
      s4[1][kt] = fx4{0.f, 0.f, 0.f, 0.f};
      for (int kc = 0; kc < 4; ++kc) {
        int pos = (kc * 4 + quad) ^ ln;
        short8 kf = *(const short8*)&kb_[(kt * 16 + ln) * 128 + pos * 8];
        s4[0][kt] = __builtin_amdgcn_mfma_f32_16x16x32_bf16(kf, qf[0][kc], s4[0][kt], 0, 0, 0);
        s4[1][kt] = __builtin_amdgcn_mfma_f32_16x16x32_bf16(kf, qf[1][kc], s4[1][kt], 0, 0, 0);
      }
    }
    short4b pb[2][4];
    for (int s = 0; s < 2; ++s)
      for (int kt = 0; kt < 4; ++kt) {
        int kvb = jt * 64 + kt * 16 + quad * 4;
        float p[4];
        for (int r = 0; r < 4; ++r)
          p[r] = exp2f(fmaf(s4[s][kt][r], ATT_C1, -ATT_C2));
        if (jt * 64 + kt * 16 + 15 > qt * 128 + wave * 32 + s * 16) {
          for (int r = 0; r < 4; ++r) if (kvb + r > qg[s]) p[r] = 0.f;
        }
        l_loc[s] += (p[0] + p[1]) + (p[2] + p[3]);
        pb[s][kt] = short4b{ bf_t(p[0]), bf_t(p[1]), bf_t(p[2]), bf_t(p[3]) };
      }
    const unsigned short* vb_ = &vbuf[cur][0];
    for (int kh2 = 0; kh2 < 2; ++kh2) {
      for (int dt = 0; dt < 8; ++dt) {
        int row = dt * 16 + ln;
        int pos = (kh2 * 4 + quad) ^ (ln & 7);
        short8 va = *(const short8*)&vb_[row * 64 + pos * 8];
        short4b va0 = { va[0], va[1], va[2], va[3] };
        short4b va1 = { va[4], va[5], va[6], va[7] };
        for (int s = 0; s < 2; ++s) {
          accy[s][dt] = __builtin_amdgcn_mfma_f32_16x16x16bf16_1k(
              va0, pb[s][kh2 * 2], accy[s][dt], 0, 0, 0);
          accy[s][dt] = __builtin_amdgcn_mfma_f32_16x16x16bf16_1k(
              va1, pb[s][kh2 * 2 + 1], accy[s][dt], 0, 0, 0);
        }
      }
    }
  }

  int cbase = qt + ((qt - 1) * (qt - 1)) / 4;     // qt=0 -> 0
  const long pp = (long)(h * 72 + cbase + ch);
  for (int s = 0; s < 2; ++s) {
    float l = l_loc[s];
    l += __shfl_xor(l, 16);
    l += __shfl_xor(l, 32);
    int q = wave * 32 + s * 16 + ln;
    if (quad == 0) lp[pp * 128 + q] = l;
    unsigned short* yb = Yp + pp * 16384 + (long)q * 128;
    for (int dt = 0; dt < 8; ++dt) {
      ushort4v o;
      for (int r = 0; r < 4; ++r) o[r] = f2bf(accy[s][dt][r]);
      *(ushort4v*)(yb + dt * 16 + quad * 4) = o;
    }
  }
}

// ---------------------------------------------------------------------------
// Kernel 3b: combine partials: Y = (sum_c Yp)/(sum_c lp) -> ybf [t][h*128+d].
// ---------------------------------------------------------------------------
__global__ __launch_bounds__(256) void attn_combine(
    const unsigned short* __restrict__ Yp, const float* __restrict__ lp,
    unsigned short* __restrict__ y) {
  const int bx = blockIdx.x, h = blockIdx.y;
  const int qt = bx >> 1, sub = bx & 1;
  const int tid = threadIdx.x;
  const int row = sub * 64 + (tid >> 2), cb = (tid & 3) * 32;
  const int nc = (qt >> 1) + 1;
  const int cbase = qt + ((qt - 1) * (qt - 1)) / 4;
  float acc[32];
  for (int j = 0; j < 32; ++j) acc[j] = 0.f;
  float ltot = 0.f;
  for (int c = 0; c < nc; ++c) {
    long pp = (long)(h * 72 + cbase + c);
    const unsigned short* ys = Yp + pp * 16384 + (long)row * 128 + cb;
    ltot += lp[pp * 128 + row];
    for (int q8 = 0; q8 < 4; ++q8) {
      ushort8 v = *(const ushort8*)(ys + q8 * 8);
      for (int j = 0; j < 8; ++j) acc[q8 * 8 + j] += bf2f(v[j]);
    }
  }
  float inv = 1.f / ltot;
  unsigned short* dst = y + (long)(qt * 128 + row) * 1024 + h * 128 + cb;
  for (int q8 = 0; q8 < 4; ++q8) {
    ushort8 o;
    for (int j = 0; j < 8; ++j) o[j] = f2bf(acc[q8 * 8 + j] * inv);
    *(ushort8*)(dst + q8 * 8) = o;
  }
}

// ---------------------------------------------------------------------------
// Workspace layout (bytes), ~42 MB. Liveness-ordered (stream serializes):
//   12582912 : x_bf  (4MB)  cast3 -> gemm1
//   16777216 : wqkv  (6MB)  cast3 -> gemm1     (NOTHING may write here
//                                               between cast3 and gemm1!)
//   23068672 : wproj (2MB)  cast3 -> gemm2
//   25165824 : qhat (4MB) | 29360128 : khat (4MB) | 33554432 : vt (4MB)
//              gemm1 -> attn_part
//   0        : Yp bf16 18.87MB  attn_part -> attn_combine (overwrites
//              x_bf/wqkv, both dead by then)
//   18874368 : lp fp32 (295KB)  attn_part -> attn_combine (wqkv dead)
//   37748736 : rope cos (256KB) @37748736, sin @38010880  rope_tab -> gemm1
//              (inside ybf region, dead until attn_combine)  [R8 BUG FIX:
//              was inside wqkv -> NaN bf16 weights]
//   37748736 : ybf (4MB)  attn_combine -> gemm2 (rope tables dead)
// ---------------------------------------------------------------------------
extern "C" void kernel_launch(void* const* d_in, const int* in_sizes, int n_in,
                              void* d_out, int out_size, void* d_ws, size_t ws_size,
                              hipStream_t stream) {
  const float* x       = (const float*)d_in[0];
  const float* ve      = (const float*)d_in[1];
  const float* qkv_w   = (const float*)d_in[2];
  const float* lambdas = (const float*)d_in[3];
  const float* c_proj  = (const float*)d_in[4];
  char* ws = (char*)d_ws;
  unsigned short* x_bf   = (unsigned short*)(ws + 12582912);
  unsigned short* wqkv   = (unsigned short*)(ws + 16777216);
  unsigned short* wproj  = (unsigned short*)(ws + 23068672);
  unsigned short* qhat   = (unsigned short*)(ws + 25165824);
  unsigned short* khat   = (unsigned short*)(ws + 29360128);
  unsigned short* vtb    = (unsigned short*)(ws + 33554432);
  unsigned short* ybf    = (unsigned short*)(ws + 37748736);
  unsigned short* Yp     = (unsigned short*)(ws);
  float*          lpart  = (float*)(ws + 18874368);
  float*          ropec  = (float*)(ws + 37748736);   // in ybf region (dead)
  float*          ropes  = (float*)(ws + 38010880);
  float* out = (float*)d_out;

  cast3_kernel<<<6144, 256, 0, stream>>>(x, qkv_w, c_proj, x_bf);
  rope_tab<<<256, 256, 0, stream>>>(ropec, ropes);
  gemm1_fused<<<dim3(24, 32), 256, 0, stream>>>(
      x_bf, wqkv, ve, lambdas, ropec, ropes, qhat, khat, vtb);
  attn_part<<<dim3(16, 8, 8), 256, 0, stream>>>(qhat, khat, vtb, Yp, lpart);
  attn_combine<<<dim3(32, 8), 256, 0, stream>>>(Yp, lpart, ybf);
  gemm_bt5<false, 64, 64, 64><<<dim3(16, 32), 256, 0, stream>>>(ybf, wproj, out, 2048, 1024, 1024);
}

// Round 10
// 197.023 us; speedup vs baseline: 1.1403x; 1.1403x over previous
//
#include <hip/hip_runtime.h>

// ---------------------------------------------------------------------------
// CausalSelfAttention (B=1, T=2048, DIM=1024, H=8, hd=128, scale=0.12)
// R10: recombination of best measured pieces:
//   - gemm1: R6's fast shape (BM=64,BN=128,BK=64, 768 blocks, dbuf,
//     1 barrier/iter) writing plain qkv_bf (NO fused epilogue — R8/R9's
//     fusion tripled the kernel: 30 -> 94 us).
//   - prep: R7's parallel kernels (qk_norm_rope2: 1 wave/row, 8192 blocks;
//     v_combine_t: interleaved vt transpose) — measured ~9 us combined.
//   - attention: R6/R9 attn_part (dbuf K+V, 1 barrier/jt, S^T trick,
//     16x16x16 PV with P already in B-layout) + combine.
//   - gemm2: 64x64x64, 512 blocks.
// MFMA layouts (m89/m91): x32: A[m=ln][k=quad*8+j]; x16: A[m=ln][k=quad*4+j];
//   B mirrors with n=ln; C/D: row=quad*4+reg, col=ln (quad=lane>>4)
// ---------------------------------------------------------------------------

typedef __attribute__((ext_vector_type(8))) short short8;      // 8 bf16
typedef __attribute__((ext_vector_type(4))) short short4b;     // 4 bf16
typedef __attribute__((ext_vector_type(4))) float fx4;         // MFMA acc
typedef __attribute__((ext_vector_type(8))) unsigned short ushort8;
typedef __attribute__((ext_vector_type(4))) unsigned short ushort4v;
typedef __attribute__((ext_vector_type(2))) unsigned short ushort2v;
typedef __attribute__((ext_vector_type(4))) float float4v;

#define T_SEQ 2048
#define NH 8
#define HD 128

__device__ __forceinline__ unsigned short f2bf(float f) {
  union { float f; unsigned u; } v; v.f = f;
  unsigned u = v.u;
  u += 0x7fffu + ((u >> 16) & 1u);        // RNE, finite inputs only
  return (unsigned short)(u >> 16);
}
__device__ __forceinline__ short bf_t(float f) {  // truncate (fast)
  union { float f; unsigned u; } v; v.f = f;
  return (short)(v.u >> 16);
}
__device__ __forceinline__ float bf2f(unsigned short h) {
  union { unsigned u; float f; } v; v.u = ((unsigned)h) << 16;
  return v.f;
}

// async global->LDS, 16B/lane; LDS dest = wave-uniform base + lane*16
typedef __attribute__((address_space(1))) unsigned int glb_u32;
typedef __attribute__((address_space(3))) unsigned int lds_u32;
__device__ __forceinline__ void gl_lds16(const unsigned short* g, unsigned short* l) {
  __builtin_amdgcn_global_load_lds((const glb_u32*)g, (lds_u32*)l, 16, 0, 0);
}

// ---------------------------------------------------------------------------
// Kernel 0: cast x (2M), qkv_w (3M), c_proj_w (1M) fp32 -> bf16 contiguous.
// ---------------------------------------------------------------------------
__global__ __launch_bounds__(256) void cast3_kernel(
    const float* __restrict__ x, const float* __restrict__ w1,
    const float* __restrict__ w2, unsigned short* __restrict__ o) {
  long q = (long)blockIdx.x * 256 + threadIdx.x;   // quad index
  const float* src;
  if (q < 524288)        src = x  + 4 * q;
  else if (q < 1310720)  src = w1 + 4 * (q - 524288);
  else                   src = w2 + 4 * (q - 1310720);
  float4v v = *(const float4v*)src;
  ushort4v r;
  r[0] = f2bf(v[0]); r[1] = f2bf(v[1]); r[2] = f2bf(v[2]); r[3] = f2bf(v[3]);
  *(ushort4v*)(o + 4 * q) = r;
}

// ---------------------------------------------------------------------------
// GEMM (BT): C[M,N] = A[M,K]*B[N,K]^T, bf16 in / fp32 acc. Tile BM x BN x BK,
// 4 waves (2x2). Double-buffered LDS, ONE barrier per K-iter; next-iter
// global_load_lds issued right after the barrier (full-iteration prefetch).
// Row of BK shorts = CPR 16B chunks; chunk c of row m at pos c^((m>>1)&CPR-1).
// ---------------------------------------------------------------------------
template <bool OUT_BF16, int BM, int BN, int BK>
__global__ __launch_bounds__(256) void gemm_bt5(
    const unsigned short* __restrict__ A, const unsigned short* __restrict__ B,
    void* __restrict__ Cp, int M, int N, int K) {
  constexpr int MT = BM / 32;
  constexpr int NT = BN / 32;
  constexpr int KQ = BK / 32;
  constexpr int CPR = BK / 8;
  constexpr int ASEG = BM * BK / 512;
  constexpr int NLOAD = (BM + BN) * BK / 512 / 4;
  __shared__ unsigned short a_sh[2][BM * BK];
  __shared__ unsigned short b_sh[2][BN * BK];
  const int tid = threadIdx.x;
  const int wave = tid >> 6, lane = tid & 63;
  const int ln = lane & 15, quad = lane >> 4;
  const int wm = wave & 1, wn = wave >> 1;
  const long arow0 = (long)blockIdx.y * BM;
  const long brow0 = (long)blockIdx.x * BN;

  const unsigned short* gsrc[NLOAD];
  unsigned short* ldst[NLOAD];
  int bstr[NLOAD];
  for (int i = 0; i < NLOAD; ++i) {
    int s = wave * NLOAD + i;
    int isB = s >= ASEG;
    int srel = isB ? s - ASEG : s;
    int li = srel * 64 + lane;
    int row = li / CPR, posc = li % CPR;
    int c = posc ^ ((row >> 1) & (CPR - 1));
    gsrc[i] = (isB ? B + brow0 * (long)K : A + arow0 * (long)K)
              + (long)row * K + c * 8;
    ldst[i] = (isB ? &b_sh[0][0] : &a_sh[0][0]) + srel * 512;
    bstr[i] = (isB ? BN : BM) * BK;
  }
  for (int i = 0; i < NLOAD; ++i) gl_lds16(gsrc[i], ldst[i]);

  fx4 acc[MT][NT] = {};
  int cur = 0;
  for (int k0 = 0; k0 < K; k0 += BK, cur ^= 1) {
    __syncthreads();                          // drains async; publishes cur
    if (k0 + BK < K)                          // prefetch next into cur^1
      for (int i = 0; i < NLOAD; ++i)
        gl_lds16(gsrc[i] + k0 + BK, ldst[i] + (cur ^ 1) * bstr[i]);
    const unsigned short* ash = &a_sh[cur][0];
    const unsigned short* bsh = &b_sh[cur][0];
    short8 af[KQ][MT], bfr[KQ][NT];
    for (int kq = 0; kq < KQ; ++kq) {
      for (int mt = 0; mt < MT; ++mt) {
        int m = wm * (BM / 2) + mt * 16 + ln;
        int pos = (kq * 4 + quad) ^ ((m >> 1) & (CPR - 1));
        af[kq][mt] = *(const short8*)&ash[m * BK + pos * 8];
      }
      for (int nt = 0; nt < NT; ++nt) {
        int n = wn * (BN / 2) + nt * 16 + ln;
        int pos = (kq * 4 + quad) ^ ((n >> 1) & (CPR - 1));
        bfr[kq][nt] = *(const short8*)&bsh[n * BK + pos * 8];
      }
    }
    for (int kq = 0; kq < KQ; ++kq)
      for (int mt = 0; mt < MT; ++mt)
        for (int nt = 0; nt < NT; ++nt)
          acc[mt][nt] = __builtin_amdgcn_mfma_f32_16x16x32_bf16(
              af[kq][mt], bfr[kq][nt], acc[mt][nt], 0, 0, 0);
  }
  for (int mt = 0; mt < MT; ++mt)
    for (int nt = 0; nt < NT; ++nt)
      for (int r = 0; r < 4; ++r) {
        long row = arow0 + wm * (BM / 2) + mt * 16 + quad * 4 + r;
        long col = brow0 + wn * (BN / 2) + nt * 16 + ln;
        float v = acc[mt][nt][r];
        if constexpr (OUT_BF16)
          ((unsigned short*)Cp)[row * N + col] = f2bf(v);
        else
          ((float*)Cp)[row * N + col] = v;
      }
}

// ---------------------------------------------------------------------------
// Kernel 2a: RMSNorm + rotary, ONE WAVE PER (t, h, which) ROW (R7, ~4us).
// 32768 waves = 8192 blocks. Lane d<64 handles rotary pair (d, d+64).
// qhat/khat layout: [h][t][d] bf16.
// ---------------------------------------------------------------------------
__global__ __launch_bounds__(256) void qk_norm_rope2(
    const unsigned short* __restrict__ qkv, unsigned short* __restrict__ qh,
    unsigned short* __restrict__ kh) {
  const int idx = blockIdx.x * 4 + (threadIdx.x >> 6);   // 0..32767
  const int lane = threadIdx.x & 63;
  const int which = idx & 1, h = (idx >> 1) & 7, t = idx >> 4;
  const unsigned short* src = qkv + (long)t * 3072 + which * 1024 + h * 128;
  float x1 = bf2f(src[lane]);
  float x2 = bf2f(src[64 + lane]);
  float ss = x1 * x1 + x2 * x2;
  for (int off = 1; off < 64; off <<= 1) ss += __shfl_xor(ss, off);
  float rn = rsqrtf(ss * (1.0f / 128.0f) + 1.1920929e-7f);
  float ang = (lane < 32) ? exp2f(-10.0f * (float)lane / 31.0f) : 0.0f;
  float th = (float)t * ang;
  float sv = __sinf(th), cv = __cosf(th);
  float y1 = ( x1 * cv + x2 * sv) * rn;
  float y2 = (-x1 * sv + x2 * cv) * rn;
  unsigned short* dst = (which ? kh : qh) + ((long)h * T_SEQ + t) * 128;
  dst[lane] = f2bf(y1);
  dst[64 + lane] = f2bf(y2);
}

// ---------------------------------------------------------------------------
// Kernel 2b: v = l0*v + l1*ve, transpose to vt[h][d][t'] bf16 where within
// each 64-t tile positions are kt-interleaved (p = kt1*32 + q4*8 + kt0*4 + j)
// for direct 16x16x16 PV A-frag b128 reads.
// ---------------------------------------------------------------------------
__global__ __launch_bounds__(256) void v_combine_t(
    const unsigned short* __restrict__ qkv, const float* __restrict__ ve,
    const float* __restrict__ lambdas, unsigned short* __restrict__ vt) {
  __shared__ unsigned short lt[128 * 72];
  const int tt = blockIdx.x, h = blockIdx.y;
  const int tid = threadIdx.x;
  const float l0 = lambdas[0], l1 = lambdas[1];
  const int r = tid >> 2, cb = (tid & 3) * 32;
  const unsigned short* vs = qkv + (long)(tt * 64 + r) * 3072 + 2048 + h * 128 + cb;
  const float* es = ve + (long)(tt * 64 + r) * 1024 + h * 128 + cb;
  ushort8 vv[4];
  for (int q = 0; q < 4; ++q) vv[q] = *(const ushort8*)(vs + 8 * q);
  float4v ee[8];
  for (int q = 0; q < 8; ++q) ee[q] = *(const float4v*)(es + 4 * q);
  for (int j = 0; j < 32; ++j) {
    float v = bf2f(vv[j >> 3][j & 7]) * l0 + ee[j >> 2][j & 3] * l1;
    lt[(cb + j) * 72 + r] = f2bf(v);
  }
  __syncthreads();
  const int d = tid >> 1, half = tid & 1;
  unsigned short* dst = vt + ((long)h * HD + d) * T_SEQ + tt * 64 + half * 32;
  const unsigned short* srcl = &lt[d * 72];
  for (int g = 0; g < 8; ++g) {
    int p0 = half * 32 + g * 4;
    int kv0 = ((p0 >> 5) & 1) * 32 + ((p0 >> 2) & 1) * 16 + ((p0 >> 3) & 3) * 4;
    *(ushort4v*)(dst + g * 4) = *(const ushort4v*)(srcl + kv0);
  }
}

// ---------------------------------------------------------------------------
// Kernel 3a: chunked flash attention partials (q-tile 128, 2 q-sets/wave).
// Grid (qt=16, h=8, ch=8); chunk covers 64-kv tiles [4ch, min(4ch+3, 2qt+1)].
// K,V double-buffered; ONE barrier per jt; full-iteration async prefetch.
// S^T = K*Q^T; fixed-max softmax; PV via mfma_16x16x16 (P already B-layout).
// Partials: pp=h*72+cbase(qt)+ch; Yp bf16 [pp][128][128], lp fp32 [pp][128].
// ---------------------------------------------------------------------------
#define ATT_C1 0.17312340490667562f   // 0.12 * log2(e)
#define ATT_C2 23.083120654223415f    // 16   * log2(e)

__global__ __launch_bounds__(256, 2) void attn_part(
    const unsigned short* __restrict__ qh, const unsigned short* __restrict__ kh,
    const unsigned short* __restrict__ vt, unsigned short* __restrict__ Yp,
    float* __restrict__ lp) {
  __shared__ unsigned short kbuf[2][8192];    // 2 x 16KB: K tile [64][128]
  __shared__ unsigned short vbuf[2][8192];    // 2 x 16KB: V^T tile [128][64]
  const int tid = threadIdx.x;
  const int wave = tid >> 6, lane = tid & 63;
  const int ln = lane & 15, quad = lane >> 4;
  const int qt = blockIdx.x, h = blockIdx.y, ch = blockIdx.z;
  const int jmax = 2 * qt + 1;
  const int j0 = ch * 4;
  if (j0 > jmax) return;                      // uniform per block
  const int j1 = min(j0 + 3, jmax);

  int qg[2];
  short8 qf[2][4];
  for (int s = 0; s < 2; ++s) {
    qg[s] = qt * 128 + wave * 32 + s * 16 + ln;
    const unsigned short* qbase = qh + ((long)h * T_SEQ + qg[s]) * 128;
    for (int kc = 0; kc < 4; ++kc)
      qf[s][kc] = *(const short8*)(qbase + kc * 32 + quad * 8);
  }
  fx4 accy[2][8] = {};
  float l_loc[2] = {0.f, 0.f};

  const unsigned short* kg[4]; unsigned short* kl[4];
  const unsigned short* vg[4]; unsigned short* vl[4];
  for (int i = 0; i < 4; ++i) {
    int s = wave * 4 + i;
    { int li = s * 64 + lane; int row = li >> 4, posc = li & 15;
      int c = posc ^ (row & 15);
      kg[i] = kh + ((long)h * T_SEQ + row) * 128 + c * 8;
      kl[i] = &kbuf[0][s * 512]; }
    { int li = s * 64 + lane; int row = li >> 3, posc = li & 7;
      int c = posc ^ (row & 7);
      vg[i] = vt + ((long)h * HD + row) * T_SEQ + c * 8;
      vl[i] = &vbuf[0][s * 512]; }
  }
  for (int i = 0; i < 4; ++i) gl_lds16(kg[i] + (long)j0 * 8192, kl[i]);
  for (int i = 0; i < 4; ++i) gl_lds16(vg[i] + (long)j0 * 64, vl[i]);

  int cur = 0;
  for (int jt = j0; jt <= j1; ++jt, cur ^= 1) {
    __syncthreads();                // drains async loads; publishes buf[cur]
    if (jt < j1) {                  // full-iteration prefetch into cur^1
      int nb = (cur ^ 1) * 8192;
      for (int i = 0; i < 4; ++i) gl_lds16(kg[i] + (long)(jt + 1) * 8192, kl[i] + nb);
      for (int i = 0; i < 4; ++i) gl_lds16(vg[i] + (long)(jt + 1) * 64, vl[i] + nb);
    }
    const unsigned short* kb_ = &kbuf[cur][0];
    fx4 s4[2][4];
    for (int kt = 0; kt < 4; ++kt) {
      s4[0][kt] = fx4{0.f, 0.f, 0.f, 0.f};
      s4[1][kt] = fx4{0.f, 0.f, 0.f, 0.f};
      for (int kc = 0; kc < 4; ++kc) {
        int pos = (kc * 4 + quad) ^ ln;
        short8 kf = *(const short8*)&kb_[(kt * 16 + ln) * 128 + pos * 8];
        s4[0][kt] = __builtin_amdgcn_mfma_f32_16x16x32_bf16(kf, qf[0][kc], s4[0][kt], 0, 0, 0);
        s4[1][kt] = __builtin_amdgcn_mfma_f32_16x16x32_bf16(kf, qf[1][kc], s4[1][kt], 0, 0, 0);
      }
    }
    short4b pb[2][4];
    for (int s = 0; s < 2; ++s)
      for (int kt = 0; kt < 4; ++kt) {
        int kvb = jt * 64 + kt * 16 + quad * 4;
        float p[4];
        for (int r = 0; r < 4; ++r)
          p[r] = exp2f(fmaf(s4[s][kt][r], ATT_C1, -ATT_C2));
        if (jt * 64 + kt * 16 + 15 > qt * 128 + wave * 32 + s * 16) {
          for (int r = 0; r < 4; ++r) if (kvb + r > qg[s]) p[r] = 0.f;
        }
        l_loc[s] += (p[0] + p[1]) + (p[2] + p[3]);
        pb[s][kt] = short4b{ bf_t(p[0]), bf_t(p[1]), bf_t(p[2]), bf_t(p[3]) };
      }
    const unsigned short* vb_ = &vbuf[cur][0];
    for (int kh2 = 0; kh2 < 2; ++kh2) {
      for (int dt = 0; dt < 8; ++dt) {
        int row = dt * 16 + ln;
        int pos = (kh2 * 4 + quad) ^ (ln & 7);
        short8 va = *(const short8*)&vb_[row * 64 + pos * 8];
        short4b va0 = { va[0], va[1], va[2], va[3] };
        short4b va1 = { va[4], va[5], va[6], va[7] };
        for (int s = 0; s < 2; ++s) {
          accy[s][dt] = __builtin_amdgcn_mfma_f32_16x16x16bf16_1k(
              va0, pb[s][kh2 * 2], accy[s][dt], 0, 0, 0);
          accy[s][dt] = __builtin_amdgcn_mfma_f32_16x16x16bf16_1k(
              va1, pb[s][kh2 * 2 + 1], accy[s][dt], 0, 0, 0);
        }
      }
    }
  }

  int cbase = qt + ((qt - 1) * (qt - 1)) / 4;     // qt=0 -> 0
  const long pp = (long)(h * 72 + cbase + ch);
  for (int s = 0; s < 2; ++s) {
    float l = l_loc[s];
    l += __shfl_xor(l, 16);
    l += __shfl_xor(l, 32);
    int q = wave * 32 + s * 16 + ln;
    if (quad == 0) lp[pp * 128 + q] = l;
    unsigned short* yb = Yp + pp * 16384 + (long)q * 128;
    for (int dt = 0; dt < 8; ++dt) {
      ushort4v o;
      for (int r = 0; r < 4; ++r) o[r] = f2bf(accy[s][dt][r]);
      *(ushort4v*)(yb + dt * 16 + quad * 4) = o;
    }
  }
}

// ---------------------------------------------------------------------------
// Kernel 3b: combine partials: Y = (sum_c Yp)/(sum_c lp) -> ybf [t][h*128+d].
// ---------------------------------------------------------------------------
__global__ __launch_bounds__(256) void attn_combine(
    const unsigned short* __restrict__ Yp, const float* __restrict__ lp,
    unsigned short* __restrict__ y) {
  const int bx = blockIdx.x, h = blockIdx.y;
  const int qt = bx >> 1, sub = bx & 1;
  const int tid = threadIdx.x;
  const int row = sub * 64 + (tid >> 2), cb = (tid & 3) * 32;
  const int nc = (qt >> 1) + 1;
  const int cbase = qt + ((qt - 1) * (qt - 1)) / 4;
  float acc[32];
  for (int j = 0; j < 32; ++j) acc[j] = 0.f;
  float ltot = 0.f;
  for (int c = 0; c < nc; ++c) {
    long pp = (long)(h * 72 + cbase + c);
    const unsigned short* ys = Yp + pp * 16384 + (long)row * 128 + cb;
    ltot += lp[pp * 128 + row];
    for (int q8 = 0; q8 < 4; ++q8) {
      ushort8 v = *(const ushort8*)(ys + q8 * 8);
      for (int j = 0; j < 8; ++j) acc[q8 * 8 + j] += bf2f(v[j]);
    }
  }
  float inv = 1.f / ltot;
  unsigned short* dst = y + (long)(qt * 128 + row) * 1024 + h * 128 + cb;
  for (int q8 = 0; q8 < 4; ++q8) {
    ushort8 o;
    for (int j = 0; j < 8; ++j) o[j] = f2bf(acc[q8 * 8 + j] * inv);
    *(ushort8*)(dst + q8 * 8) = o;
  }
}

// ---------------------------------------------------------------------------
// Workspace layout (bytes), ~42 MB (stream-ordered liveness):
//   0        : qkv_bf (12MB)  gemm1 -> prep   | later: Yp bf16 18.87MB
//   12582912 : x_bf   (4MB)   cast3 -> gemm1  |   (attn_part -> combine)
//   16777216 : wqkv   (6MB)   cast3 -> gemm1  | later: lp fp32 @18874368
//   23068672 : wproj  (2MB)   cast3 -> gemm2
//   25165824 : qhat (4MB) | 29360128 : khat (4MB) | 33554432 : vt (4MB)
//   37748736 : ybf (4MB)   combine -> gemm2
// ---------------------------------------------------------------------------
extern "C" void kernel_launch(void* const* d_in, const int* in_sizes, int n_in,
                              void* d_out, int out_size, void* d_ws, size_t ws_size,
                              hipStream_t stream) {
  const float* x       = (const float*)d_in[0];
  const float* ve      = (const float*)d_in[1];
  const float* qkv_w   = (const float*)d_in[2];
  const float* lambdas = (const float*)d_in[3];
  const float* c_proj  = (const float*)d_in[4];
  char* ws = (char*)d_ws;
  unsigned short* qkv_bf = (unsigned short*)(ws);
  unsigned short* x_bf   = (unsigned short*)(ws + 12582912);
  unsigned short* wqkv   = (unsigned short*)(ws + 16777216);
  unsigned short* wproj  = (unsigned short*)(ws + 23068672);
  unsigned short* qhat   = (unsigned short*)(ws + 25165824);
  unsigned short* khat   = (unsigned short*)(ws + 29360128);
  unsigned short* vtb    = (unsigned short*)(ws + 33554432);
  unsigned short* ybf    = (unsigned short*)(ws + 37748736);
  unsigned short* Yp     = (unsigned short*)(ws);              // reuse
  float*          lpart  = (float*)(ws + 18874368);            // reuse
  float* out = (float*)d_out;

  cast3_kernel<<<6144, 256, 0, stream>>>(x, qkv_w, c_proj, x_bf);
  gemm_bt5<true, 64, 128, 64><<<dim3(24, 32), 256, 0, stream>>>(
      x_bf, wqkv, qkv_bf, 2048, 3072, 1024);
  qk_norm_rope2<<<8192, 256, 0, stream>>>(qkv_bf, qhat, khat);
  v_combine_t<<<dim3(32, 8), 256, 0, stream>>>(qkv_bf, ve, lambdas, vtb);
  attn_part<<<dim3(16, 8, 8), 256, 0, stream>>>(qhat, khat, vtb, Yp, lpart);
  attn_combine<<<dim3(32, 8), 256, 0, stream>>>(Yp, lpart, ybf);
  gemm_bt5<false, 64, 64, 64><<<dim3(16, 32), 256, 0, stream>>>(
      ybf, wproj, out, 2048, 1024, 1024);
}